// Round 2
// baseline (1231.188 us; speedup 1.0000x reference)
//
#include <hip/hip_runtime.h>
#include <hip/hip_bf16.h>
#include <math.h>

#define N_ 4
#define C_ 128
#define H_ 256
#define W_ 256
#define HW_ (H_*W_)
#define BN_EPS 1e-5f

typedef __attribute__((ext_vector_type(8))) short bf16x8;
typedef __attribute__((ext_vector_type(4))) float floatx4;

__device__ __forceinline__ short f2bf(float v) {
    __hip_bfloat16 h = __float2bfloat16(v);
    return __builtin_bit_cast(short, h);
}
__device__ __forceinline__ float bf2f(short s) {
    unsigned u = ((unsigned)(unsigned short)s) << 16;
    return __builtin_bit_cast(float, u);
}

// ---------------- prep: weight swizzles into MFMA A-frag order (bf16) ----------------
__global__ __launch_bounds__(256) void k_prep(const float* __restrict__ refine_w,
                                              const float* __restrict__ joint_w,
                                              const float* __restrict__ dyn_w,
                                              short* __restrict__ rwf,
                                              short* __restrict__ jwf,
                                              float* __restrict__ dwp) {
    int i = blockIdx.x * 256 + threadIdx.x;
    if (i < 32768) {
        int j      = i & 7;
        int lane   = (i >> 3) & 63;
        int cotile = (i >> 9) & 7;
        int cic    = (i >> 12) & 7;
        int co = cotile * 16 + (lane & 15);
        int ii = cic * 32 + (lane >> 4) * 8 + j;
        rwf[i] = f2bf(refine_w[co * 256 + ii]);
    }
    if (i < 147456) {
        int j      = i & 7;
        int lane   = (i >> 3) & 63;
        int cotile = (i >> 9) & 7;
        int cic    = (i >> 12) & 3;
        int t      = i >> 14;            // 0..8
        int co = cotile * 16 + (lane & 15);
        int ci = cic * 32 + (lane >> 4) * 8 + j;
        jwf[i] = f2bf(joint_w[(co * 128 + ci) * 9 + t]);
    }
    if (i < 13824) {
        int t  = i % 12;
        int kc = i / 12;       // c*9 + k
        int k  = kc % 9;
        int c  = kc / 9;
        dwp[i] = (t < 9) ? dyn_w[(k * C_ + c) * 9 + t] : 0.f;
    }
}

// ---------------- kernel 1: dyn_kernel = L1-normalized conv(ms; C->9) ----------------
#define DSTR 24   // row stride: (ty*24+tx)%32 covers each bank exactly 2x -> free
__global__ __launch_bounds__(256) void k_dyn(const float* __restrict__ ms,
                                             const float* __restrict__ dwp,
                                             const float* __restrict__ dyn_b,
                                             float* __restrict__ dk) {
    __shared__ float ms_s[8 * 18 * DSTR];
    int tid = threadIdx.x;
    int tx = tid & 15, ty = tid >> 4;
    int gid = (blockIdx.z * 16 + blockIdx.y) * 16 + blockIdx.x;
    int lg = (gid & 7) * 128 + (gid >> 3);
    int n = lg >> 8;
    int rem = lg & 255;
    int h0 = (rem >> 4) * 16, w0 = (rem & 15) * 16;

    float acc[9];
#pragma unroll
    for (int k = 0; k < 9; k++) acc[k] = dyn_b[k];

    for (int cc = 0; cc < 16; cc++) {
        __syncthreads();
        for (int e = tid; e < 8 * 18 * 18; e += 256) {
            int ch = e / 324, r = (e % 324) / 18, cl = e % 18;
            int gh = h0 + r - 1, gw = w0 + cl - 1;
            float v = 0.f;
            if (gh >= 0 && gh < H_ && gw >= 0 && gw < W_)
                v = ms[(size_t)(n * C_ + cc * 8 + ch) * HW_ + gh * W_ + gw];
            ms_s[ch * (18 * DSTR) + r * DSTR + cl] = v;
        }
        __syncthreads();
        for (int c8 = 0; c8 < 8; c8++) {
            int c = cc * 8 + c8;
            float m[9];
#pragma unroll
            for (int dy = 0; dy < 3; dy++)
#pragma unroll
                for (int dx = 0; dx < 3; dx++)
                    m[dy * 3 + dx] = ms_s[c8 * (18 * DSTR) + (ty + dy) * DSTR + tx + dx];
            const float* wp = dwp + c * 108;   // c*9*12
#pragma unroll
            for (int k = 0; k < 9; k++) {
                const float* w = wp + k * 12;
                floatx4 wa = *(const floatx4*)w;
                floatx4 wb = *(const floatx4*)(w + 4);
                float w8 = w[8];
                float a = acc[k];
                a = fmaf(m[0], wa[0], a);
                a = fmaf(m[1], wa[1], a);
                a = fmaf(m[2], wa[2], a);
                a = fmaf(m[3], wa[3], a);
                a = fmaf(m[4], wb[0], a);
                a = fmaf(m[5], wb[1], a);
                a = fmaf(m[6], wb[2], a);
                a = fmaf(m[7], wb[3], a);
                a = fmaf(m[8], w8, a);
                acc[k] = a;
            }
        }
    }
    float s = 0.f;
#pragma unroll
    for (int k = 0; k < 9; k++) s += fabsf(acc[k]);
    float inv = 1.f / s;
    int h = h0 + ty, w = w0 + tx;
#pragma unroll
    for (int k = 0; k < 9; k++)
        dk[(size_t)(n * 9 + k) * HW_ + h * W_ + w] = acc[k] * inv;
}

// ---------------- kernel 2 (MFMA): refine 1x1; emits fusedbf & pbf in NHWC bf16 ----------------
#define AIP 264
#define MSP 120   // 10 rows x stride 12: (py*12+pxx)%32 = exact 2-way -> free
__global__ __launch_bounds__(256) void k_fused(const float* __restrict__ ms,
                                               const float* __restrict__ dk,
                                               const float* __restrict__ coef,
                                               const float* __restrict__ fix_w,
                                               const float* __restrict__ bn1_g,
                                               const float* __restrict__ bn1_b,
                                               const float* __restrict__ bn1_m,
                                               const float* __restrict__ bn1_v,
                                               const float* __restrict__ bn2_g,
                                               const float* __restrict__ bn2_b,
                                               const float* __restrict__ bn2_m,
                                               const float* __restrict__ bn2_v,
                                               const short* __restrict__ rwf,
                                               const float* __restrict__ refine_b,
                                               short* __restrict__ fusedbf,
                                               short* __restrict__ pbf) {
    __shared__ short act_s[64 * AIP];
    __shared__ float ms_s[4 * 8 * MSP];   // per-wave 8ch x 10x12 slab
    __shared__ float bnp_s[128 * 4];
    int tid = threadIdx.x;
    int lane = tid & 63;
    int wave = __builtin_amdgcn_readfirstlane(tid >> 6);
    int gid = (blockIdx.z * 32 + blockIdx.y) * 32 + blockIdx.x;
    int lg = (gid & 7) * 512 + (gid >> 3);
    int n = lg >> 10;
    int rem = lg & 1023;
    int h0 = (rem >> 5) * 8, w0 = (rem & 31) * 8;

    // BN params once per block (was: 2x rsqrt per (g,c8) per thread)
    if (tid < 128) {
        int c = tid;
        float i1 = bn1_g[c] * rsqrtf(bn1_v[c] + BN_EPS);
        float b1 = bn1_b[c] - bn1_m[c] * i1;
        float i2 = bn2_g[c] * rsqrtf(bn2_v[c] + BN_EPS);
        float b2 = bn2_b[c] - bn2_m[c] * i2;
        bnp_s[c * 4 + 0] = i1; bnp_s[c * 4 + 1] = b1;
        bnp_s[c * 4 + 2] = i2; bnp_s[c * 4 + 3] = b2;
    }

    int py = lane >> 3, pxx = lane & 7;
    float dkr[9];
#pragma unroll
    for (int t = 0; t < 9; t++)
        dkr[t] = dk[(size_t)(n * 9 + t) * HW_ + (h0 + py) * W_ + (w0 + pxx)];
    __syncthreads();

    float* msw = ms_s + wave * (8 * MSP);
    int sch = lane >> 3, scl = lane & 7;

    for (int g = 0; g < 4; g++) {
        int cc = wave * 4 + g;
        const float* gb = ms + (size_t)(n * C_ + cc * 8 + sch) * HW_;
        float* wb = msw + sch * MSP;
        // rows 0..9 x cols 0..7 : div-free, r is a compile-time constant
#pragma unroll
        for (int r = 0; r < 10; r++) {
            int gh = h0 + r - 1;
            int gw = w0 + scl - 1;
            float v = 0.f;
            if (gh >= 0 && gh < H_ && gw >= 0)     // gw <= w0+6 <= 254 < W_
                v = gb[gh * W_ + gw];
            wb[r * 12 + scl] = v;
        }
        // cols 8,9 x rows 0..7
#pragma unroll
        for (int s = 0; s < 2; s++) {
            int r = lane & 7;
            int gh = h0 + r - 1;
            int gw = w0 + 7 + s;
            float v = 0.f;
            if (gh >= 0 && gw < W_)                // gh <= h0+6 <= 254 < H_
                v = gb[gh * W_ + gw];
            wb[r * 12 + 8 + s] = v;
        }
        // cols 8,9 x rows 8,9 (32 lanes)
        if (lane < 32) {
            int ch2 = lane >> 2;
            int r = 8 + ((lane >> 1) & 1);
            int s = lane & 1;
            int gh = h0 + r - 1;
            int gw = w0 + 7 + s;
            float v = 0.f;
            if (gh < H_ && gw < W_)                // gh >= h0+7 >= 0
                v = ms[(size_t)(n * C_ + cc * 8 + ch2) * HW_ + gh * W_ + gw];
            msw[ch2 * MSP + r * 12 + 8 + s] = v;
        }

        bf16x8 d8v, f8v;
#pragma unroll
        for (int c8 = 0; c8 < 8; c8++) {
            int c = cc * 8 + c8;
            float4 bp = *(const float4*)(bnp_s + c * 4);   // uniform -> broadcast
            float m[9];
#pragma unroll
            for (int dy = 0; dy < 3; dy++)
#pragma unroll
                for (int dx = 0; dx < 3; dx++)
                    m[dy * 3 + dx] = msw[c8 * MSP + (py + dy) * 12 + pxx + dx];
            float dyn = 0.f, fix = 0.f;
#pragma unroll
            for (int t = 0; t < 9; t++) {
                dyn = fmaf(m[t], dkr[t], dyn);
                fix = fmaf(m[t], fix_w[c * 9 + t], fix);
            }
            dyn = fmaxf(fmaf(dyn, bp.z, bp.w), 0.f);
            fix = fmaxf(fmaf(fix, bp.x, bp.y), 0.f);
            d8v[c8] = f2bf(dyn);
            f8v[c8] = f2bf(fix);
        }
        // one conflict-free b128 write per buffer (was 16x 8-way-conflicted b16)
        *(bf16x8*)(act_s + lane * AIP + cc * 8) = d8v;
        *(bf16x8*)(act_s + lane * AIP + 128 + cc * 8) = f8v;
    }
    __syncthreads();

    // GEMM: D[co][px] = rwf x act, K=256
    int cl16 = lane & 15;
    int q = lane >> 4;
    int pxb = wave * 16;

    floatx4 acc[8];
#pragma unroll
    for (int ct = 0; ct < 8; ct++) acc[ct] = (floatx4){0.f, 0.f, 0.f, 0.f};

    const bf16x8* rwv = (const bf16x8*)rwf;
#pragma unroll
    for (int cic = 0; cic < 8; cic++) {
        bf16x8 B = *(const bf16x8*)(act_s + (pxb + cl16) * AIP + q * 8 + cic * 32);
        const bf16x8* Ap = rwv + cic * 8 * 64 + lane;
        bf16x8 A[8];
#pragma unroll
        for (int ct = 0; ct < 8; ct++) A[ct] = Ap[ct * 64];
#pragma unroll
        for (int ct = 0; ct < 8; ct++)
            acc[ct] = __builtin_amdgcn_mfma_f32_16x16x32_bf16(A[ct], B, acc[ct], 0, 0, 0);
    }

    int px = pxb + cl16;
    int h = h0 + (px >> 3), w = w0 + (px & 7);
    size_t spi = ((size_t)(n * H_) + h) * W_ + w;
#pragma unroll
    for (int ct = 0; ct < 8; ct++) {
        int co0 = ct * 16 + q * 4;
        float cf[4];
#pragma unroll
        for (int r = 0; r < 4; r++)
            cf[r] = coef[(size_t)(n * C_ + co0 + r) * HW_ + h * W_ + w];
        short4 fb, pb;
        float f0 = acc[ct][0] + refine_b[co0 + 0];
        float f1 = acc[ct][1] + refine_b[co0 + 1];
        float f2_ = acc[ct][2] + refine_b[co0 + 2];
        float f3 = acc[ct][3] + refine_b[co0 + 3];
        fb.x = f2bf(f0);  fb.y = f2bf(f1);  fb.z = f2bf(f2_);  fb.w = f2bf(f3);
        pb.x = f2bf(f0 + cf[0]); pb.y = f2bf(f1 + cf[1]);
        pb.z = f2bf(f2_ + cf[2]); pb.w = f2bf(f3 + cf[3]);
        *(short4*)(fusedbf + spi * 128 + co0) = fb;
        *(short4*)(pbf + spi * 128 + co0) = pb;
    }
}

// ---------------- kernel 3 (MFMA): out = gate(sigmoid(conv3x3(p))) ----------------
// Wave split transposed: wave owns 2 co-tiles x all 8 px-rows.
// A (jwf) loads: 288 -> 72 per thread; B from LDS, conflict-free under CIP=136.
#define CIP 136   // 272 B row = 17 x 16B granules -> (sp+g)%8 uniform
__global__ __launch_bounds__(256, 3) void k_out(const float* __restrict__ coef,
                                                const short* __restrict__ fusedbf,
                                                const short* __restrict__ pbf,
                                                const short* __restrict__ jwf,
                                                const float* __restrict__ joint_b,
                                                float* __restrict__ out) {
    __shared__ short p_s[180 * CIP];    // [(row*18+col)][ci], rows 10, cols 18
    int tid = threadIdx.x;
    int gid = (blockIdx.z * 32 + blockIdx.y) * 16 + blockIdx.x;
    int lg = (gid & 7) * 256 + (gid >> 3);
    int n = lg >> 9;
    int rem = lg & 511;
    int h0 = (rem >> 4) * 8, w0 = (rem & 15) * 16;

#pragma unroll
    for (int it = 0; it < 12; it++) {
        int e = it * 256 + tid;
        if (e < 2880) {
            int sp = e >> 4, g = e & 15;
            int row = sp / 18, col = sp - row * 18;
            int gh = h0 + row - 1, gw = w0 + col - 1;
            uint4 v = {0u, 0u, 0u, 0u};
            if (gh >= 0 && gh < H_ && gw >= 0 && gw < W_)
                v = *(const uint4*)(pbf + (((size_t)n * H_ + gh) * W_ + gw) * 128 + g * 8);
            *(uint4*)(p_s + sp * CIP + g * 8) = v;
        }
    }
    __syncthreads();

    int lane = tid & 63;
    int wave = __builtin_amdgcn_readfirstlane(tid >> 6);
    int c = lane & 15;
    int q = lane >> 4;

    floatx4 acc[2][8];
#pragma unroll
    for (int i = 0; i < 2; i++)
#pragma unroll
        for (int p = 0; p < 8; p++)
            acc[i][p] = (floatx4){0.f, 0.f, 0.f, 0.f};

    const bf16x8* jwv = (const bf16x8*)jwf;

    for (int t = 0; t < 9; t++) {
        int dy = t / 3, dx = t - dy * 3;
#pragma unroll
        for (int cic = 0; cic < 4; cic++) {
            const bf16x8* Ap = jwv + ((t * 4 + cic) * 8 + wave * 2) * 64 + lane;
            bf16x8 A0 = Ap[0];
            bf16x8 A1 = Ap[64];
            int sb = (dy * 18 + c + dx) * CIP + q * 8 + cic * 32;
#pragma unroll
            for (int p = 0; p < 8; p++) {
                bf16x8 B = *(const bf16x8*)(p_s + sb + p * (18 * CIP));
                acc[0][p] = __builtin_amdgcn_mfma_f32_16x16x32_bf16(A0, B, acc[0][p], 0, 0, 0);
                acc[1][p] = __builtin_amdgcn_mfma_f32_16x16x32_bf16(A1, B, acc[1][p], 0, 0, 0);
            }
        }
    }

    int w = w0 + c;
#pragma unroll
    for (int p = 0; p < 8; p++) {
        int h = h0 + p;
        size_t spi = ((size_t)(n * H_) + h) * W_ + w;
#pragma unroll
        for (int i = 0; i < 2; i++) {
            int co0 = (wave * 2 + i) * 16 + q * 4;
            short4 fb = *(const short4*)(fusedbf + spi * 128 + co0);
            float fv[4] = {bf2f(fb.x), bf2f(fb.y), bf2f(fb.z), bf2f(fb.w)};
#pragma unroll
            for (int r = 0; r < 4; r++) {
                int co = co0 + r;
                size_t idx = (size_t)(n * C_ + co) * HW_ + h * W_ + w;
                float z = acc[i][p][r] + joint_b[co];
                float p2 = 1.f / (1.f + __expf(-z));
                float f = fv[r], cf = coef[idx];
                out[idx] = f + p2 * (cf - f);
            }
        }
    }
}

extern "C" void kernel_launch(void* const* d_in, const int* in_sizes, int n_in,
                              void* d_out, int out_size, void* d_ws, size_t ws_size,
                              hipStream_t stream) {
    const float* coef     = (const float*)d_in[0];
    const float* ms       = (const float*)d_in[1];
    const float* fix_w    = (const float*)d_in[2];
    const float* bn1_g    = (const float*)d_in[3];
    const float* bn1_b    = (const float*)d_in[4];
    const float* bn1_m    = (const float*)d_in[5];
    const float* bn1_v    = (const float*)d_in[6];
    const float* dyn_w    = (const float*)d_in[7];
    const float* dyn_b    = (const float*)d_in[8];
    const float* bn2_g    = (const float*)d_in[9];
    const float* bn2_b    = (const float*)d_in[10];
    const float* bn2_m    = (const float*)d_in[11];
    const float* bn2_v    = (const float*)d_in[12];
    const float* refine_w = (const float*)d_in[13];
    const float* refine_b = (const float*)d_in[14];
    const float* joint_w  = (const float*)d_in[15];
    const float* joint_b  = (const float*)d_in[16];
    float* out = (float*)d_out;

    short* fusedbf = (short*)d_ws;                          // 33554432 bf16
    short* pbf     = fusedbf + (size_t)N_ * C_ * HW_;       // 33554432 bf16
    float* dk      = (float*)(pbf + (size_t)N_ * C_ * HW_); // 2359296 f32
    short* jwf     = (short*)(dk + (size_t)N_ * 9 * HW_);   // 147456 bf16
    short* rwf     = jwf + 147456;                          // 32768 bf16
    // dwp aliases the head of fusedbf: written by k_prep, read by k_dyn,
    // dead by the time k_fused overwrites fusedbf (stream-serialized).
    float* dwp     = (float*)fusedbf;                       // 13824 f32

    dim3 blk(256);
    k_prep<<<dim3(576), blk, 0, stream>>>(refine_w, joint_w, dyn_w, rwf, jwf, dwp);
    k_dyn<<<dim3(16, 16, 4), blk, 0, stream>>>(ms, dwp, dyn_b, dk);
    k_fused<<<dim3(32, 32, 4), blk, 0, stream>>>(ms, dk, coef, fix_w,
                                                 bn1_g, bn1_b, bn1_m, bn1_v,
                                                 bn2_g, bn2_b, bn2_m, bn2_v,
                                                 rwf, refine_b, fusedbf, pbf);
    k_out<<<dim3(16, 32, 4), blk, 0, stream>>>(coef, fusedbf, pbf, jwf, joint_b, out);
}

// Round 3
// 914.297 us; speedup vs baseline: 1.3466x; 1.3466x over previous
//
#include <hip/hip_runtime.h>
#include <hip/hip_bf16.h>
#include <math.h>

#define N_ 4
#define C_ 128
#define H_ 256
#define W_ 256
#define HW_ (H_*W_)
#define BN_EPS 1e-5f

typedef __attribute__((ext_vector_type(8))) short bf16x8;
typedef __attribute__((ext_vector_type(4))) float floatx4;

__device__ __forceinline__ short f2bf(float v) {
    __hip_bfloat16 h = __float2bfloat16(v);
    return __builtin_bit_cast(short, h);
}
__device__ __forceinline__ float bf2f(short s) {
    unsigned u = ((unsigned)(unsigned short)s) << 16;
    return __builtin_bit_cast(float, u);
}

// ---------------- prep: weight swizzles into MFMA A-frag order (bf16) ----------------
__global__ __launch_bounds__(256) void k_prep(const float* __restrict__ refine_w,
                                              const float* __restrict__ joint_w,
                                              const float* __restrict__ dyn_w,
                                              short* __restrict__ rwf,
                                              short* __restrict__ jwf,
                                              float* __restrict__ dwp) {
    int i = blockIdx.x * 256 + threadIdx.x;
    if (i < 32768) {
        int j      = i & 7;
        int lane   = (i >> 3) & 63;
        int cotile = (i >> 9) & 7;
        int cic    = (i >> 12) & 7;
        int co = cotile * 16 + (lane & 15);
        int ii = cic * 32 + (lane >> 4) * 8 + j;
        rwf[i] = f2bf(refine_w[co * 256 + ii]);
    }
    if (i < 147456) {
        int j      = i & 7;
        int lane   = (i >> 3) & 63;
        int cotile = (i >> 9) & 7;
        int cic    = (i >> 12) & 3;
        int t      = i >> 14;            // 0..8
        int co = cotile * 16 + (lane & 15);
        int ci = cic * 32 + (lane >> 4) * 8 + j;
        jwf[i] = f2bf(joint_w[(co * 128 + ci) * 9 + t]);
    }
    if (i < 13824) {
        int t  = i % 12;
        int kc = i / 12;       // c*9 + k
        int k  = kc % 9;
        int c  = kc / 9;
        dwp[i] = (t < 9) ? dyn_w[(k * C_ + c) * 9 + t] : 0.f;
    }
}

// ---------------- kernel 1: dyn_kernel = L1-normalized conv(ms; C->9) ----------------
#define DSTR 24   // row stride: (ty*24+tx)%32 covers each bank exactly 2x -> free
__global__ __launch_bounds__(256) void k_dyn(const float* __restrict__ ms,
                                             const float* __restrict__ dwp,
                                             const float* __restrict__ dyn_b,
                                             float* __restrict__ dk) {
    __shared__ float ms_s[8 * 18 * DSTR];
    int tid = threadIdx.x;
    int tx = tid & 15, ty = tid >> 4;
    int gid = (blockIdx.z * 16 + blockIdx.y) * 16 + blockIdx.x;
    int lg = (gid & 7) * 128 + (gid >> 3);
    int n = lg >> 8;
    int rem = lg & 255;
    int h0 = (rem >> 4) * 16, w0 = (rem & 15) * 16;

    float acc[9];
#pragma unroll
    for (int k = 0; k < 9; k++) acc[k] = dyn_b[k];

    for (int cc = 0; cc < 16; cc++) {
        __syncthreads();
        for (int e = tid; e < 8 * 18 * 18; e += 256) {
            int ch = e / 324, r = (e % 324) / 18, cl = e % 18;
            int gh = h0 + r - 1, gw = w0 + cl - 1;
            float v = 0.f;
            if (gh >= 0 && gh < H_ && gw >= 0 && gw < W_)
                v = ms[(size_t)(n * C_ + cc * 8 + ch) * HW_ + gh * W_ + gw];
            ms_s[ch * (18 * DSTR) + r * DSTR + cl] = v;
        }
        __syncthreads();
        for (int c8 = 0; c8 < 8; c8++) {
            int c = cc * 8 + c8;
            float m[9];
#pragma unroll
            for (int dy = 0; dy < 3; dy++)
#pragma unroll
                for (int dx = 0; dx < 3; dx++)
                    m[dy * 3 + dx] = ms_s[c8 * (18 * DSTR) + (ty + dy) * DSTR + tx + dx];
            const float* wp = dwp + c * 108;   // c*9*12
#pragma unroll
            for (int k = 0; k < 9; k++) {
                const float* w = wp + k * 12;
                floatx4 wa = *(const floatx4*)w;
                floatx4 wb = *(const floatx4*)(w + 4);
                float w8 = w[8];
                float a = acc[k];
                a = fmaf(m[0], wa[0], a);
                a = fmaf(m[1], wa[1], a);
                a = fmaf(m[2], wa[2], a);
                a = fmaf(m[3], wa[3], a);
                a = fmaf(m[4], wb[0], a);
                a = fmaf(m[5], wb[1], a);
                a = fmaf(m[6], wb[2], a);
                a = fmaf(m[7], wb[3], a);
                a = fmaf(m[8], w8, a);
                acc[k] = a;
            }
        }
    }
    float s = 0.f;
#pragma unroll
    for (int k = 0; k < 9; k++) s += fabsf(acc[k]);
    float inv = 1.f / s;
    int h = h0 + ty, w = w0 + tx;
#pragma unroll
    for (int k = 0; k < 9; k++)
        dk[(size_t)(n * 9 + k) * HW_ + h * W_ + w] = acc[k] * inv;
}

// ---------------- kernel 2 (MFMA): refine 1x1; emits fusedbf & pbf in NHWC bf16 ----------------
#define AIP 264
#define MSP 120   // 10 rows x stride 12: (py*12+pxx)%32 = exact 2-way -> free
__global__ __launch_bounds__(256) void k_fused(const float* __restrict__ ms,
                                               const float* __restrict__ dk,
                                               const float* __restrict__ coef,
                                               const float* __restrict__ fix_w,
                                               const float* __restrict__ bn1_g,
                                               const float* __restrict__ bn1_b,
                                               const float* __restrict__ bn1_m,
                                               const float* __restrict__ bn1_v,
                                               const float* __restrict__ bn2_g,
                                               const float* __restrict__ bn2_b,
                                               const float* __restrict__ bn2_m,
                                               const float* __restrict__ bn2_v,
                                               const short* __restrict__ rwf,
                                               const float* __restrict__ refine_b,
                                               short* __restrict__ fusedbf,
                                               short* __restrict__ pbf) {
    __shared__ short act_s[64 * AIP];
    __shared__ float ms_s[4 * 8 * MSP];   // per-wave 8ch x 10x12 slab
    __shared__ float bnp_s[128 * 4];
    int tid = threadIdx.x;
    int lane = tid & 63;
    int wave = __builtin_amdgcn_readfirstlane(tid >> 6);
    int gid = (blockIdx.z * 32 + blockIdx.y) * 32 + blockIdx.x;
    int lg = (gid & 7) * 512 + (gid >> 3);
    int n = lg >> 10;
    int rem = lg & 1023;
    int h0 = (rem >> 5) * 8, w0 = (rem & 31) * 8;

    // BN params once per block
    if (tid < 128) {
        int c = tid;
        float i1 = bn1_g[c] * rsqrtf(bn1_v[c] + BN_EPS);
        float b1 = bn1_b[c] - bn1_m[c] * i1;
        float i2 = bn2_g[c] * rsqrtf(bn2_v[c] + BN_EPS);
        float b2 = bn2_b[c] - bn2_m[c] * i2;
        bnp_s[c * 4 + 0] = i1; bnp_s[c * 4 + 1] = b1;
        bnp_s[c * 4 + 2] = i2; bnp_s[c * 4 + 3] = b2;
    }

    int py = lane >> 3, pxx = lane & 7;
    float dkr[9];
#pragma unroll
    for (int t = 0; t < 9; t++)
        dkr[t] = dk[(size_t)(n * 9 + t) * HW_ + (h0 + py) * W_ + (w0 + pxx)];
    __syncthreads();

    float* msw = ms_s + wave * (8 * MSP);
    int sch = lane >> 3, scl = lane & 7;

    for (int g = 0; g < 4; g++) {
        int cc = wave * 4 + g;
        const float* gb = ms + (size_t)(n * C_ + cc * 8 + sch) * HW_;
        float* wb = msw + sch * MSP;
#pragma unroll
        for (int r = 0; r < 10; r++) {
            int gh = h0 + r - 1;
            int gw = w0 + scl - 1;
            float v = 0.f;
            if (gh >= 0 && gh < H_ && gw >= 0)
                v = gb[gh * W_ + gw];
            wb[r * 12 + scl] = v;
        }
#pragma unroll
        for (int s = 0; s < 2; s++) {
            int r = lane & 7;
            int gh = h0 + r - 1;
            int gw = w0 + 7 + s;
            float v = 0.f;
            if (gh >= 0 && gw < W_)
                v = gb[gh * W_ + gw];
            wb[r * 12 + 8 + s] = v;
        }
        if (lane < 32) {
            int ch2 = lane >> 2;
            int r = 8 + ((lane >> 1) & 1);
            int s = lane & 1;
            int gh = h0 + r - 1;
            int gw = w0 + 7 + s;
            float v = 0.f;
            if (gh < H_ && gw < W_)
                v = ms[(size_t)(n * C_ + cc * 8 + ch2) * HW_ + gh * W_ + gw];
            msw[ch2 * MSP + r * 12 + 8 + s] = v;
        }

        bf16x8 d8v, f8v;
#pragma unroll
        for (int c8 = 0; c8 < 8; c8++) {
            int c = cc * 8 + c8;
            float4 bp = *(const float4*)(bnp_s + c * 4);
            float m[9];
#pragma unroll
            for (int dy = 0; dy < 3; dy++)
#pragma unroll
                for (int dx = 0; dx < 3; dx++)
                    m[dy * 3 + dx] = msw[c8 * MSP + (py + dy) * 12 + pxx + dx];
            float dyn = 0.f, fix = 0.f;
#pragma unroll
            for (int t = 0; t < 9; t++) {
                dyn = fmaf(m[t], dkr[t], dyn);
                fix = fmaf(m[t], fix_w[c * 9 + t], fix);
            }
            dyn = fmaxf(fmaf(dyn, bp.z, bp.w), 0.f);
            fix = fmaxf(fmaf(fix, bp.x, bp.y), 0.f);
            d8v[c8] = f2bf(dyn);
            f8v[c8] = f2bf(fix);
        }
        *(bf16x8*)(act_s + lane * AIP + cc * 8) = d8v;
        *(bf16x8*)(act_s + lane * AIP + 128 + cc * 8) = f8v;
    }
    __syncthreads();

    // GEMM: D[co][px] = rwf x act, K=256
    int cl16 = lane & 15;
    int q = lane >> 4;
    int pxb = wave * 16;

    floatx4 acc[8];
#pragma unroll
    for (int ct = 0; ct < 8; ct++) acc[ct] = (floatx4){0.f, 0.f, 0.f, 0.f};

    const bf16x8* rwv = (const bf16x8*)rwf;
#pragma unroll
    for (int cic = 0; cic < 8; cic++) {
        bf16x8 B = *(const bf16x8*)(act_s + (pxb + cl16) * AIP + q * 8 + cic * 32);
        const bf16x8* Ap = rwv + cic * 8 * 64 + lane;
        bf16x8 A[8];
#pragma unroll
        for (int ct = 0; ct < 8; ct++) A[ct] = Ap[ct * 64];
#pragma unroll
        for (int ct = 0; ct < 8; ct++)
            acc[ct] = __builtin_amdgcn_mfma_f32_16x16x32_bf16(A[ct], B, acc[ct], 0, 0, 0);
    }

    int px = pxb + cl16;
    int h = h0 + (px >> 3), w = w0 + (px & 7);
    size_t spi = ((size_t)(n * H_) + h) * W_ + w;
#pragma unroll
    for (int ct = 0; ct < 8; ct++) {
        int co0 = ct * 16 + q * 4;
        float cf[4];
#pragma unroll
        for (int r = 0; r < 4; r++)
            cf[r] = coef[(size_t)(n * C_ + co0 + r) * HW_ + h * W_ + w];
        short4 fb, pb;
        float f0 = acc[ct][0] + refine_b[co0 + 0];
        float f1 = acc[ct][1] + refine_b[co0 + 1];
        float f2_ = acc[ct][2] + refine_b[co0 + 2];
        float f3 = acc[ct][3] + refine_b[co0 + 3];
        fb.x = f2bf(f0);  fb.y = f2bf(f1);  fb.z = f2bf(f2_);  fb.w = f2bf(f3);
        pb.x = f2bf(f0 + cf[0]); pb.y = f2bf(f1 + cf[1]);
        pb.z = f2bf(f2_ + cf[2]); pb.w = f2bf(f3 + cf[3]);
        *(short4*)(fusedbf + spi * 128 + co0) = fb;
        *(short4*)(pbf + spi * 128 + co0) = pb;
    }
}

// ---------------- kernel 3 (MFMA): out = gate(sigmoid(conv3x3(p))) ----------------
// Round-1 structure (proven <=278 us): waves own 2 py-rows, full co range.
#define CIP 136   // 272 B row = 17 x 16B granules -> conflict-free b128
__global__ __launch_bounds__(256, 3) void k_out(const float* __restrict__ coef,
                                                const short* __restrict__ fusedbf,
                                                const short* __restrict__ pbf,
                                                const short* __restrict__ jwf,
                                                const float* __restrict__ joint_b,
                                                float* __restrict__ out) {
    __shared__ short p_s[180 * CIP];    // [(row*18+col)][ci], rows 10, cols 18
    int tid = threadIdx.x;
    int gid = (blockIdx.z * 32 + blockIdx.y) * 16 + blockIdx.x;
    int lg = (gid & 7) * 256 + (gid >> 3);
    int n = lg >> 9;
    int rem = lg & 511;
    int h0 = (rem >> 4) * 8, w0 = (rem & 15) * 16;

#pragma unroll
    for (int it = 0; it < 12; it++) {
        int e = it * 256 + tid;
        if (e < 2880) {
            int sp = e >> 4, g = e & 15;
            int row = sp / 18, col = sp - row * 18;
            int gh = h0 + row - 1, gw = w0 + col - 1;
            uint4 v = {0u, 0u, 0u, 0u};
            if (gh >= 0 && gh < H_ && gw >= 0 && gw < W_)
                v = *(const uint4*)(pbf + (((size_t)n * H_ + gh) * W_ + gw) * 128 + g * 8);
            *(uint4*)(p_s + sp * CIP + g * 8) = v;
        }
    }
    __syncthreads();

    int lane = tid & 63;
    int wave = __builtin_amdgcn_readfirstlane(tid >> 6);
    int c = lane & 15;
    int q = lane >> 4;
    int py0 = wave;
    int py1 = wave + 4;

    floatx4 acc[8][2];
#pragma unroll
    for (int ct = 0; ct < 8; ct++)
#pragma unroll
        for (int p = 0; p < 2; p++)
            acc[ct][p] = (floatx4){0.f, 0.f, 0.f, 0.f};

    const bf16x8* jwv = (const bf16x8*)jwf;

    for (int t = 0; t < 9; t++) {
        int dy = t / 3, dx = t - dy * 3;
        int sb0 = ((py0 + dy) * 18 + c + dx) * CIP + q * 8;
        int sb1 = ((py1 + dy) * 18 + c + dx) * CIP + q * 8;
#pragma unroll
        for (int cic = 0; cic < 4; cic++) {
            bf16x8 B0 = *(const bf16x8*)(p_s + sb0 + cic * 32);
            bf16x8 B1 = *(const bf16x8*)(p_s + sb1 + cic * 32);
            const bf16x8* Ap = jwv + ((t * 4 + cic) * 8) * 64 + lane;
            bf16x8 A[8];
#pragma unroll
            for (int ct = 0; ct < 8; ct++) A[ct] = Ap[ct * 64];
#pragma unroll
            for (int ct = 0; ct < 8; ct++) {
                acc[ct][0] = __builtin_amdgcn_mfma_f32_16x16x32_bf16(A[ct], B0, acc[ct][0], 0, 0, 0);
                acc[ct][1] = __builtin_amdgcn_mfma_f32_16x16x32_bf16(A[ct], B1, acc[ct][1], 0, 0, 0);
            }
        }
    }

    int w = w0 + c;
#pragma unroll
    for (int p = 0; p < 2; p++) {
        int h = h0 + (p == 0 ? py0 : py1);
        size_t spi = ((size_t)(n * H_) + h) * W_ + w;
#pragma unroll
        for (int ct = 0; ct < 8; ct++) {
            int co0 = ct * 16 + q * 4;
            short4 fb = *(const short4*)(fusedbf + spi * 128 + co0);
            float fv[4] = {bf2f(fb.x), bf2f(fb.y), bf2f(fb.z), bf2f(fb.w)};
#pragma unroll
            for (int r = 0; r < 4; r++) {
                int co = co0 + r;
                size_t idx = (size_t)(n * C_ + co) * HW_ + h * W_ + w;
                float z = acc[ct][p][r] + joint_b[co];
                float p2 = 1.f / (1.f + __expf(-z));
                float f = fv[r], cf = coef[idx];
                out[idx] = f + p2 * (cf - f);
            }
        }
    }
}

extern "C" void kernel_launch(void* const* d_in, const int* in_sizes, int n_in,
                              void* d_out, int out_size, void* d_ws, size_t ws_size,
                              hipStream_t stream) {
    const float* coef     = (const float*)d_in[0];
    const float* ms       = (const float*)d_in[1];
    const float* fix_w    = (const float*)d_in[2];
    const float* bn1_g    = (const float*)d_in[3];
    const float* bn1_b    = (const float*)d_in[4];
    const float* bn1_m    = (const float*)d_in[5];
    const float* bn1_v    = (const float*)d_in[6];
    const float* dyn_w    = (const float*)d_in[7];
    const float* dyn_b    = (const float*)d_in[8];
    const float* bn2_g    = (const float*)d_in[9];
    const float* bn2_b    = (const float*)d_in[10];
    const float* bn2_m    = (const float*)d_in[11];
    const float* bn2_v    = (const float*)d_in[12];
    const float* refine_w = (const float*)d_in[13];
    const float* refine_b = (const float*)d_in[14];
    const float* joint_w  = (const float*)d_in[15];
    const float* joint_b  = (const float*)d_in[16];
    float* out = (float*)d_out;

    short* fusedbf = (short*)d_ws;                          // 33554432 bf16
    short* pbf     = fusedbf + (size_t)N_ * C_ * HW_;       // 33554432 bf16
    float* dk      = (float*)(pbf + (size_t)N_ * C_ * HW_); // 2359296 f32
    short* jwf     = (short*)(dk + (size_t)N_ * 9 * HW_);   // 147456 bf16
    short* rwf     = jwf + 147456;                          // 32768 bf16
    float* dwp     = (float*)fusedbf;                       // 13824 f32 (aliased; dead before k_fused)

    dim3 blk(256);
    k_prep<<<dim3(576), blk, 0, stream>>>(refine_w, joint_w, dyn_w, rwf, jwf, dwp);
    k_dyn<<<dim3(16, 16, 4), blk, 0, stream>>>(ms, dwp, dyn_b, dk);
    k_fused<<<dim3(32, 32, 4), blk, 0, stream>>>(ms, dk, coef, fix_w,
                                                 bn1_g, bn1_b, bn1_m, bn1_v,
                                                 bn2_g, bn2_b, bn2_m, bn2_v,
                                                 rwf, refine_b, fusedbf, pbf);
    k_out<<<dim3(16, 32, 4), blk, 0, stream>>>(coef, fusedbf, pbf, jwf, joint_b, out);
}